// Round 1
// 143.963 us; speedup vs baseline: 1.0648x; 1.0648x over previous
//
#include <hip/hip_runtime.h>
#include <hip/hip_bf16.h>
#include <math.h>

#define Nn 4096
#define Hdim 256
#define Edim 128
#define Cdim 32
#define Vdim 64
#define Kdim 20
#define G4H 1024
#define OUTS 513

#define NB 8
#define LMAXL 64
#define MAXG (NB * LMAXL)      // 512 lstm slots
#define MAXT2 192              // loss slots
#define GRID (MAXG + MAXT2)    // 704

// workspace layout (ints): [0..31] cntK, [32..63] cntC,
// [64 ..) rowsK[20][512], then rowsC[32][256]
#define SK 512
#define SC 256
#define RK_OFF 64
#define RC_OFF (RK_OFF + Kdim * SK)   // 10304

typedef short bf16x8 __attribute__((ext_vector_type(8)));
typedef float f32x4 __attribute__((ext_vector_type(4)));

__device__ __forceinline__ float sigmoidf_(float x) { return 1.0f / (1.0f + expf(-x)); }

__device__ __forceinline__ bf16x8 cvt8(float4 f0, float4 f1) {
    bf16x8 r;
    __hip_bfloat16 h;
    h = __float2bfloat16(f0.x); r[0] = *(short*)&h;
    h = __float2bfloat16(f0.y); r[1] = *(short*)&h;
    h = __float2bfloat16(f0.z); r[2] = *(short*)&h;
    h = __float2bfloat16(f0.w); r[3] = *(short*)&h;
    h = __float2bfloat16(f1.x); r[4] = *(short*)&h;
    h = __float2bfloat16(f1.y); r[5] = *(short*)&h;
    h = __float2bfloat16(f1.z); r[6] = *(short*)&h;
    h = __float2bfloat16(f1.w); r[7] = *(short*)&h;
    return r;
}

__device__ __forceinline__ void gl_lds16(const float* g, void* l) {
    __builtin_amdgcn_global_load_lds((const __attribute__((address_space(1))) void*)g,
                                     (__attribute__((address_space(3))) void*)l, 16, 0, 0);
}

__device__ __forceinline__ int swz(int r) { return ((r & 3) << 1) | ((r >> 2) & 1); }

// ================= setup: bucket rows by cell_id / category into workspace =================
__global__ __launch_bounds__(1024) void k_setup(const int* __restrict__ cell_id,
                                                const int* __restrict__ category,
                                                int* __restrict__ ws) {
    __shared__ int cnt[32];
    int t = threadIdx.x;
    if (t < 32) cnt[t] = 0;
    __syncthreads();
    int i0 = t * 4;
    if (blockIdx.x == 0) {
        int4 v = ((const int4*)cell_id)[t];
        int r;
        r = atomicAdd(&cnt[v.x], 1); if (r < SK) ws[RK_OFF + v.x * SK + r] = i0 + 0;
        r = atomicAdd(&cnt[v.y], 1); if (r < SK) ws[RK_OFF + v.y * SK + r] = i0 + 1;
        r = atomicAdd(&cnt[v.z], 1); if (r < SK) ws[RK_OFF + v.z * SK + r] = i0 + 2;
        r = atomicAdd(&cnt[v.w], 1); if (r < SK) ws[RK_OFF + v.w * SK + r] = i0 + 3;
        __syncthreads();
        if (t < 32) ws[t] = min(cnt[t], SK);
    } else {
        int4 v = ((const int4*)category)[t];
        int r;
        r = atomicAdd(&cnt[v.x], 1); if (r < SC) ws[RC_OFF + v.x * SC + r] = i0 + 0;
        r = atomicAdd(&cnt[v.y], 1); if (r < SC) ws[RC_OFF + v.y * SC + r] = i0 + 1;
        r = atomicAdd(&cnt[v.z], 1); if (r < SC) ws[RC_OFF + v.z * SC + r] = i0 + 2;
        r = atomicAdd(&cnt[v.w], 1); if (r < SC) ws[RC_OFF + v.w * SC + r] = i0 + 3;
        __syncthreads();
        if (t < 32) ws[32 + t] = min(cnt[t], SC);
    }
}

// ================= main fused kernel (double-buffered staging) =================
__global__ __launch_bounds__(256, 2) void k_main(
    const float* __restrict__ vec, const float* __restrict__ inp,
    const float* __restrict__ h_prev, const float* __restrict__ c_prev,
    const float* __restrict__ Wlin, const float* __restrict__ blin,
    const float* __restrict__ Wec, const float* __restrict__ bec,
    const float* __restrict__ Wrel, const float* __restrict__ brel,
    const float* __restrict__ W_ih, const float* __restrict__ b_ih,
    const float* __restrict__ W_hh, const float* __restrict__ b_hh,
    const int* __restrict__ true_idx, const int* __restrict__ ec_idx, const int* __restrict__ rel_idx,
    const int* __restrict__ ws,
    float* __restrict__ out)
{
    __shared__ __align__(16) char smem[81920];   // lstm: 2 x (32K W + 8K X); loss: 2 x 14336 dbuf + Lg

    int t = threadIdx.x;
    int w = t >> 6, l = t & 63;
    int l15 = l & 15, quad = l >> 4;
    int lrow8 = l >> 3, lslot = l & 7;
    bool is_lstm = blockIdx.x < MAXG;

    // ---- cheap decode from precomputed counts ----
    int* cnt = (int*)smem;
    if (t < 32) cnt[t] = ws[(is_lstm ? 0 : 32) + t];
    __syncthreads();

    int myk, s_idx, hb0 = 0, rcount;
    if (is_lstm) {
        int b = blockIdx.x & 7, pos = blockIdx.x >> 3;
        int u = -1, sf = 0, acc = 0;
        for (int uu = b; uu < Kdim * 4; uu += NB) {
            int n = (cnt[uu >> 2] + 63) >> 6;
            if (u < 0 && pos < acc + n) { u = uu; sf = pos - acc; }
            acc += n;
        }
        if (u < 0) return;
        myk = u >> 2; hb0 = (u & 3) * 64; s_idx = sf;
        rcount = min(64, cnt[myk] - s_idx * 64);
    } else {
        int slot = blockIdx.x - MAXG;
        int u = -1, sf = 0, acc = 0;
        for (int m = 0; m < Cdim; m++) {
            int n = (cnt[m] + 31) >> 5;
            if (u < 0 && slot < acc + n) { u = m; sf = slot - acc; }
            acc += n;
        }
        if (u < 0) return;
        myk = u; s_idx = sf;
        rcount = min(32, cnt[myk] - s_idx * 32);
    }

    const int* rlist = is_lstm ? (ws + RK_OFF + myk * SK + s_idx * 64)
                               : (ws + RC_OFF + myk * SC + s_idx * 32);
    int li = is_lstm ? l : (l & 31);
    int reg_row = rlist[li < rcount ? li : rcount - 1];
    int swz_l = swz(l15);
    int p0 = (quad * 2) ^ swz_l;
    __syncthreads();   // cnt reads done before staging overwrites smem head

    if (is_lstm) {
        // ============ LSTM: 64 rows x (64 h x 4 gates), K=384, fp32 DMA BK=32, dbuf ============
        const float* Wih_k = W_ih + (size_t)myk * G4H * Edim;
        const float* Whh_k = W_hh + (size_t)myk * G4H * Hdim;

        int xr0 = w * 16 + lrow8;
        int xr1 = xr0 + 8;
        int xrow0 = __shfl(reg_row, xr0);
        int xrow1 = __shfl(reg_row, xr1);
        int xg0 = lslot ^ swz(xr0);
        int xg1 = lslot ^ swz(xr1);

        auto stageL = [&](int st, int d) {
            float* Wb = (float*)(smem + d * 40960);
            float* Xb = (float*)(smem + d * 40960 + 32768);
            int k0 = st * 32;
            const float* Wsrc; int stride, ko;
            if (k0 < Edim) { Wsrc = Wih_k; stride = Edim; ko = k0; }
            else           { Wsrc = Whh_k; stride = Hdim; ko = k0 - Edim; }
            #pragma unroll
            for (int j = 0; j < 8; j++) {
                int r = w * 64 + j * 8 + lrow8;
                int g = lslot ^ swz(r);
                int gate = r >> 6, hl = r & 63;
                gl_lds16(Wsrc + (size_t)(gate * Hdim + hb0 + hl) * stride + ko + g * 4,
                         Wb + (w * 64 + j * 8) * 32);
            }
            const float* Xs0 = (k0 < Edim) ? inp + (size_t)xrow0 * Edim + ko
                                           : h_prev + (size_t)xrow0 * Hdim + ko;
            const float* Xs1 = (k0 < Edim) ? inp + (size_t)xrow1 * Edim + ko
                                           : h_prev + (size_t)xrow1 * Hdim + ko;
            gl_lds16(Xs0 + xg0 * 4, Xb + (w * 16) * 32);
            gl_lds16(Xs1 + xg1 * 4, Xb + (w * 16 + 8) * 32);
        };

        f32x4 acc[4][4];
        #pragma unroll
        for (int m = 0; m < 4; m++)
            #pragma unroll
            for (int g = 0; g < 4; g++)
                acc[m][g] = (f32x4){0.f, 0.f, 0.f, 0.f};

        stageL(0, 0);
        for (int st = 0; st < 12; st++) {
            int cur = st & 1;
            if (st < 11) stageL(st + 1, cur ^ 1);    // prefetch next stage into other buffer
            if (st < 11) asm volatile("s_waitcnt vmcnt(10)" ::: "memory");  // 10 ops/thread/stage in flight
            else         asm volatile("s_waitcnt vmcnt(0)" ::: "memory");
            __builtin_amdgcn_s_barrier();
            __builtin_amdgcn_sched_barrier(0);

            float* Wb = (float*)(smem + cur * 40960);
            float* Xb = (float*)(smem + cur * 40960 + 32768);
            bf16x8 af[4], bfr[4];
            #pragma unroll
            for (int m = 0; m < 4; m++) {
                int row = m * 16 + l15;
                float4 lo = *(float4*)(Xb + row * 32 + p0 * 4);
                float4 hi = *(float4*)(Xb + row * 32 + (p0 ^ 1) * 4);
                af[m] = cvt8(lo, hi);
            }
            #pragma unroll
            for (int g = 0; g < 4; g++) {
                int row = g * 64 + w * 16 + l15;
                float4 lo = *(float4*)(Wb + row * 32 + p0 * 4);
                float4 hi = *(float4*)(Wb + row * 32 + (p0 ^ 1) * 4);
                bfr[g] = cvt8(lo, hi);
            }
            #pragma unroll
            for (int m = 0; m < 4; m++)
                #pragma unroll
                for (int g = 0; g < 4; g++)
                    acc[m][g] = __builtin_amdgcn_mfma_f32_16x16x32_bf16(af[m], bfr[g], acc[m][g], 0, 0, 0);

            __builtin_amdgcn_sched_barrier(0);
            __builtin_amdgcn_s_barrier();            // my reads of buf[cur] consumed; safe to overwrite next iter
        }

        int h = hb0 + w * 16 + l15;
        float bs[4];
        #pragma unroll
        for (int g = 0; g < 4; g++)
            bs[g] = b_ih[(size_t)myk * G4H + g * Hdim + h] + b_hh[(size_t)myk * G4H + g * Hdim + h];

        #pragma unroll
        for (int m = 0; m < 4; m++) {
            #pragma unroll
            for (int reg = 0; reg < 4; reg++) {
                int r = m * 16 + quad * 4 + reg;
                int row = __shfl(reg_row, r);
                if (r < rcount) {
                    float iv = acc[m][0][reg] + bs[0];
                    float fv = acc[m][1][reg] + bs[1];
                    float gv = acc[m][2][reg] + bs[2];
                    float ov = acc[m][3][reg] + bs[3];
                    float cp = c_prev[(size_t)row * Hdim + h];
                    float cn = sigmoidf_(fv) * cp + sigmoidf_(iv) * tanhf(gv);
                    float hn = sigmoidf_(ov) * tanhf(cn);
                    out[(size_t)row * OUTS + 1 + h] = hn;
                    out[(size_t)row * OUTS + 1 + Hdim + h] = cn;
                }
            }
        }
    } else {
        // ============ loss: 32 rows x 80 logits, K=256, fp32 DMA BK=32, dbuf ============
        int m2 = myk;
        int xr = w * 8 + lrow8;
        int xrow = __shfl(reg_row, xr);
        int xg = lslot ^ swz(xr);

        auto stageS = [&](int st, int d) {
            float* Wb = (float*)(smem + d * 14336);
            float* Vb = (float*)(smem + d * 14336 + 10240);
            int ko = st * 32;
            for (int n = w; n < 10; n += 4) {
                int r = n * 8 + lrow8;
                int g = lslot ^ swz(r);
                const float* srcW;
                if (r < 64)      srcW = Wlin + ((size_t)m2 * Vdim + r) * Hdim;
                else if (r < 66) srcW = Wec + (size_t)(r - 64) * Hdim;
                else if (r < 71) srcW = Wrel + (size_t)(r - 66) * Hdim;
                else             srcW = Wlin + (size_t)m2 * Vdim * Hdim;
                gl_lds16(srcW + ko + g * 4, Wb + n * 8 * 32);
            }
            gl_lds16(vec + (size_t)xrow * Hdim + ko + xg * 4, Vb + (w * 8) * 32);
        };

        f32x4 a0[2], a1[2];
        #pragma unroll
        for (int m = 0; m < 2; m++) { a0[m] = (f32x4){0.f,0.f,0.f,0.f}; a1[m] = (f32x4){0.f,0.f,0.f,0.f}; }

        stageS(0, 0);
        for (int st = 0; st < 8; st++) {
            int cur = st & 1;
            if (st < 7) stageS(st + 1, cur ^ 1);
            // waves 0,1 issue 4 DMA ops/stage; waves 2,3 issue 3
            if (st < 7) {
                if (w < 2) asm volatile("s_waitcnt vmcnt(4)" ::: "memory");
                else       asm volatile("s_waitcnt vmcnt(3)" ::: "memory");
            } else       asm volatile("s_waitcnt vmcnt(0)" ::: "memory");
            __builtin_amdgcn_s_barrier();
            __builtin_amdgcn_sched_barrier(0);

            float* Wb = (float*)(smem + cur * 14336);
            float* Vb = (float*)(smem + cur * 14336 + 10240);
            bf16x8 af[2];
            #pragma unroll
            for (int m = 0; m < 2; m++) {
                int row = m * 16 + l15;
                float4 lo = *(float4*)(Vb + row * 32 + p0 * 4);
                float4 hi = *(float4*)(Vb + row * 32 + (p0 ^ 1) * 4);
                af[m] = cvt8(lo, hi);
            }
            {
                int row = w * 16 + l15;
                float4 lo = *(float4*)(Wb + row * 32 + p0 * 4);
                float4 hi = *(float4*)(Wb + row * 32 + (p0 ^ 1) * 4);
                bf16x8 b0 = cvt8(lo, hi);
                a0[0] = __builtin_amdgcn_mfma_f32_16x16x32_bf16(af[0], b0, a0[0], 0, 0, 0);
                a0[1] = __builtin_amdgcn_mfma_f32_16x16x32_bf16(af[1], b0, a0[1], 0, 0, 0);
            }
            if (w == 3) {
                int row = 64 + l15;
                float4 lo = *(float4*)(Wb + row * 32 + p0 * 4);
                float4 hi = *(float4*)(Wb + row * 32 + (p0 ^ 1) * 4);
                bf16x8 b1 = cvt8(lo, hi);
                a1[0] = __builtin_amdgcn_mfma_f32_16x16x32_bf16(af[0], b1, a1[0], 0, 0, 0);
                a1[1] = __builtin_amdgcn_mfma_f32_16x16x32_bf16(af[1], b1, a1[1], 0, 0, 0);
            }
            __builtin_amdgcn_sched_barrier(0);
            __builtin_amdgcn_s_barrier();
        }

        float* Lg = (float*)(smem + 28672);   // 32 x 84 f32, above the double buffers
        {
            int col = w * 16 + l15;
            float bb = blin[m2 * Vdim + col];
            #pragma unroll
            for (int m = 0; m < 2; m++)
                #pragma unroll
                for (int reg = 0; reg < 4; reg++)
                    Lg[(m * 16 + quad * 4 + reg) * 84 + col] = a0[m][reg] + bb;
            if (w == 3) {
                int col1 = 64 + l15;
                float bb1 = (l15 < 2) ? bec[l15] : ((l15 < 7) ? brel[l15 - 2] : 0.f);
                #pragma unroll
                for (int m = 0; m < 2; m++)
                    #pragma unroll
                    for (int reg = 0; reg < 4; reg++)
                        Lg[(m * 16 + quad * 4 + reg) * 84 + col1] = a1[m][reg] + bb1;
            }
        }
        __syncthreads();
        for (int rr = 0; rr < 8; rr++) {
            int r = w * 8 + rr;
            if (r >= rcount) break;
            int orig = __shfl(reg_row, r);
            float lg = Lg[r * 84 + l];
            float mx = lg;
            for (int ss = 32; ss >= 1; ss >>= 1) mx = fmaxf(mx, __shfl_xor(mx, ss));
            float sm = expf(lg - mx);
            for (int ss = 32; ss >= 1; ss >>= 1) sm += __shfl_xor(sm, ss);
            float lt = __shfl(lg, true_idx[orig]);
            float loss = mx + logf(sm) - lt;
            if (l == 0) {
                float l0 = Lg[r * 84 + 64], l1 = Lg[r * 84 + 65];
                float me2 = fmaxf(l0, l1);
                loss += me2 + logf(expf(l0 - me2) + expf(l1 - me2)) - ((ec_idx[orig] == 0) ? l0 : l1);
                float rl[5] = { Lg[r * 84 + 66], Lg[r * 84 + 67], Lg[r * 84 + 68], Lg[r * 84 + 69], Lg[r * 84 + 70] };
                float mr = rl[0];
                #pragma unroll
                for (int i = 1; i < 5; i++) mr = fmaxf(mr, rl[i]);
                float sr = 0.f;
                #pragma unroll
                for (int i = 0; i < 5; i++) sr += expf(rl[i] - mr);
                loss += mr + logf(sr) - rl[rel_idx[orig]];
                out[(size_t)orig * OUTS] = loss;
            }
        }
    }
}

extern "C" void kernel_launch(void* const* d_in, const int* in_sizes, int n_in,
                              void* d_out, int out_size, void* d_ws, size_t ws_size,
                              hipStream_t stream) {
    const float* vec      = (const float*)d_in[0];
    const float* inp      = (const float*)d_in[1];
    const float* h_prev   = (const float*)d_in[2];
    const float* c_prev   = (const float*)d_in[3];
    const float* Wlin     = (const float*)d_in[4];
    const float* blin     = (const float*)d_in[5];
    const float* Wec      = (const float*)d_in[6];
    const float* bec      = (const float*)d_in[7];
    const float* Wrel     = (const float*)d_in[8];
    const float* brel     = (const float*)d_in[9];
    const float* W_ih     = (const float*)d_in[10];
    const float* b_ih     = (const float*)d_in[11];
    const float* W_hh     = (const float*)d_in[12];
    const float* b_hh     = (const float*)d_in[13];
    const int*   category = (const int*)d_in[14];
    const int*   cell_id  = (const int*)d_in[15];
    const int*   true_idx = (const int*)d_in[16];
    const int*   ec_idx   = (const int*)d_in[17];
    const int*   rel_idx  = (const int*)d_in[18];
    float* out = (float*)d_out;
    int* ws = (int*)d_ws;

    k_setup<<<2, 1024, 0, stream>>>(cell_id, category, ws);
    k_main<<<GRID, 256, 0, stream>>>(
        vec, inp, h_prev, c_prev, Wlin, blin, Wec, bec, Wrel, brel,
        W_ih, b_ih, W_hh, b_hh, true_idx, ec_idx, rel_idx, ws, out);
}